// Round 3
// baseline (76.824 us; speedup 1.0000x reference)
//
#include <hip/hip_runtime.h>
#include <math.h>

// DiffEMA: out[t] = sum_{k=0}^{K-1} alpha*c^k * x[t-k],  c = 1-alpha, x[<0]=x[0]
// Identity: out = H(u) where H = infinite IIR (y[t]=c*y[t-1]+alpha*u[t]) and
//           u[t] = x[t] - c^K * x[t-K]   (linearity + time-invariance).
// Each thread scans LSEG=16 samples fully in registers; one wave-level
// (P,V) shuffle scan + 32B LDS cross-wave exchange gives the true prefix
// state; fixup z[j] += s*c^(j+1) by linearity (no second scan pass).
// Each block covers TOTAL=4096 window samples = W_WARM=2048 warm-up (zero-init
// error c^2048 ~ 1e-9) + NB=2048 outputs. Clamping x indices to 0 reproduces
// the reference's replicate-pad exactly (pad value IS x[0]).

#define K_TAPS 700
#define W_WARM 2048
#define NB     2048
#define TOTAL  (W_WARM + NB)     // 4096
#define BLOCK  256
#define LSEG   (TOTAL / BLOCK)   // 16 samples per thread
#define NW     (BLOCK / 64)

__global__ __launch_bounds__(BLOCK)
void diffema_kernel(const float* __restrict__ x,
                    const float* __restrict__ w_alpha,
                    float* __restrict__ out, int T) {
    __shared__ float wP[NW], wV[NW];

    const int tid  = threadIdx.x;
    const int lane = tid & 63;
    const int wave = tid >> 6;
    const long t0   = (long)blockIdx.x * NB;   // first output of this block
    const long base = t0 - W_WARM;             // window start (may be < 0)
    const long segs = base + (long)tid * LSEG; // my segment's first sample

    const float wa    = w_alpha[0];
    const float alpha = 1.0f / (1.0f + expf(-wa));
    const float c     = 1.0f - alpha;
    const float cK    = powf(c, (float)K_TAPS);

    // ---- load x[seg] and x[seg-K] (float4, clamp<0 -> x[0]), form u in regs
    // segs and segs-K are multiples of 4 (K=700 divisible by 4), so each
    // float4 is either fully in-bounds or fully in the replicate-pad region.
    float u[LSEG];
    {
        float4 a[LSEG / 4], b[LSEG / 4];
        const float x0 = x[0];
#pragma unroll
        for (int i = 0; i < LSEG / 4; ++i) {
            long p = segs + 4 * i;
            if (p >= 0) a[i] = *(const float4*)(x + p);
            else        a[i] = make_float4(x0, x0, x0, x0);
            long q = p - K_TAPS;
            if (q >= 0) b[i] = *(const float4*)(x + q);
            else        b[i] = make_float4(x0, x0, x0, x0);
        }
#pragma unroll
        for (int i = 0; i < LSEG / 4; ++i) {
            u[4 * i + 0] = fmaf(-cK, b[i].x, a[i].x);
            u[4 * i + 1] = fmaf(-cK, b[i].y, a[i].y);
            u[4 * i + 2] = fmaf(-cK, b[i].z, a[i].z);
            u[4 * i + 3] = fmaf(-cK, b[i].w, a[i].w);
        }
    }

    // ---- serial zero-init scan over my segment, in place: u[j] <- z_local[j]
    float v = 0.0f;
#pragma unroll
    for (int j = 0; j < LSEG; ++j) {
        v = fmaf(c, v, alpha * u[j]);
        u[j] = v;
    }

    // ---- wave-level inclusive scan of (P=c^LSEG, V) under composition
    float P = powf(c, (float)LSEG), V = v;
#pragma unroll
    for (int d = 1; d < 64; d <<= 1) {
        float Pp = __shfl_up(P, d);
        float Vp = __shfl_up(V, d);
        if (lane >= d) { V = fmaf(P, Vp, V); P *= Pp; }
    }

    // ---- cross-wave exchange (32 B LDS, single barrier)
    if (lane == 63) { wP[wave] = P; wV[wave] = V; }
    __syncthreads();
    float prefV = 0.0f;
#pragma unroll
    for (int k = 0; k < NW - 1; ++k) {
        if (k < wave) prefV = fmaf(wP[k], prefV, wV[k]);
    }

    // exclusive prefix: true state entering my segment
    float Pex = __shfl_up(P, 1);
    float Vex = __shfl_up(V, 1);
    if (lane == 0) { Pex = 1.0f; Vex = 0.0f; }
    const float s = fmaf(Pex, prefV, Vex);

    // ---- linear fixup: z[j] = z_local[j] + s * c^(j+1)
    float m = s;
#pragma unroll
    for (int j = 0; j < LSEG; ++j) {
        m *= c;
        u[j] += m;
    }

    // ---- store (threads whose segment lies in the output region)
    if (segs >= t0) {
#pragma unroll
        for (int i = 0; i < LSEG / 4; ++i) {
            long p = segs + 4 * i;
            if (p + 3 < (long)T) {
                *(float4*)(out + p) =
                    make_float4(u[4 * i + 0], u[4 * i + 1],
                                u[4 * i + 2], u[4 * i + 3]);
            } else {                       // generic tail guard (unused at T=4M)
                for (int jj = 0; jj < 4; ++jj)
                    if (p + jj < (long)T) out[p + jj] = u[4 * i + jj];
            }
        }
    }
}

extern "C" void kernel_launch(void* const* d_in, const int* in_sizes, int n_in,
                              void* d_out, int out_size, void* d_ws, size_t ws_size,
                              hipStream_t stream) {
    const float* x       = (const float*)d_in[0];
    const float* w_alpha = (const float*)d_in[1];
    float*       out     = (float*)d_out;
    const int T = in_sizes[0];

    const int nblocks = (T + NB - 1) / NB;   // 2048 for T=4194304
    diffema_kernel<<<nblocks, BLOCK, 0, stream>>>(x, w_alpha, out, T);
}

// Round 4
// 75.684 us; speedup vs baseline: 1.0151x; 1.0151x over previous
//
#include <hip/hip_runtime.h>
#include <math.h>

// DiffEMA: out[t] = sum_{k=0}^{K-1} alpha*c^k * x[t-k],  c = 1-alpha, x[<0]=x[0]
// Identity: out = H(u), u[t] = x[t] - c^K * x[t-K]  (H = infinite IIR with
// y[t] = c*y[t-1] + alpha*u[t]).  Register-resident per-thread scan of
// LSEG=24 samples; wave (P,V) shuffle scan + 32B LDS cross-wave exchange;
// linear fixup z[j] += s*c^(j+1).  W_WARM=2048 zero-init warm-up
// (error c^2048 ~ 1e-9).  Index clamp to 0 reproduces replicate-pad exactly.
// No libm powf: c^700 by binary exponentiation (exact-ish, ~14 muls).

#define K_TAPS 700
#define W_WARM 2048
#define NB     4096
#define TOTAL  (W_WARM + NB)     // 6144
#define BLOCK  256
#define LSEG   (TOTAL / BLOCK)   // 24 samples per thread
#define NW     (BLOCK / 64)      // 4 waves

__global__ __launch_bounds__(BLOCK)
void diffema_kernel(const float* __restrict__ x,
                    const float* __restrict__ w_alpha,
                    float* __restrict__ out, int T) {
    __shared__ float wP[NW], wV[NW];

    const int tid  = threadIdx.x;
    const int lane = tid & 63;
    const int wave = tid >> 6;
    const int t0   = blockIdx.x * NB;        // first output of this block
    const int base = t0 - W_WARM;            // window start (may be < 0)
    const int segs = base + tid * LSEG;      // my segment's first sample

    // ---- constants: fast sigmoid + power-by-squaring (no libm powf)
    const float wa    = w_alpha[0];
    const float alpha = 1.0f / (1.0f + __expf(-wa));
    const float c     = 1.0f - alpha;
    const float c2 = c * c,   c4 = c2 * c2,   c8 = c4 * c4,  c16 = c8 * c8;
    const float c32 = c16*c16, c64 = c32*c32, c128 = c64*c64;
    const float c256 = c128*c128, c512 = c256*c256;
    const float cK = ((c512 * c128) * (c32 * c16)) * (c8 * c4); // c^700
    const float cL = c16 * c8;                                   // c^24

    // ---- load x[seg], x[seg-K]; form u in regs.
    // All float4s 16B-aligned: segs, K_TAPS, W_WARM, NB all multiples of 4.
    float u[LSEG];
    const bool interior = (blockIdx.x != 0) && (t0 + NB <= T);
    if (interior) {
        // fast path: every index in [0, T)
#pragma unroll
        for (int i = 0; i < LSEG / 4; ++i) {
            const float4 a = *(const float4*)(x + segs + 4 * i);
            const float4 b = *(const float4*)(x + segs + 4 * i - K_TAPS);
            u[4*i+0] = fmaf(-cK, b.x, a.x);
            u[4*i+1] = fmaf(-cK, b.y, a.y);
            u[4*i+2] = fmaf(-cK, b.z, a.z);
            u[4*i+3] = fmaf(-cK, b.w, a.w);
        }
    } else {
        // edge path: clamp left (replicate-pad = x[0]) and right (safety)
#pragma unroll
        for (int j = 0; j < LSEG; ++j) {
            int p = segs + j;
            int pc = p < 0 ? 0 : (p > T - 1 ? T - 1 : p);
            int q = p - K_TAPS;
            int qc = q < 0 ? 0 : (q > T - 1 ? T - 1 : q);
            u[j] = fmaf(-cK, x[qc], x[pc]);
        }
    }

    // ---- serial zero-init scan, in place
    float v = 0.0f;
#pragma unroll
    for (int j = 0; j < LSEG; ++j) {
        v = fmaf(c, v, alpha * u[j]);
        u[j] = v;
    }

    // ---- wave-level inclusive scan of (P=c^LSEG, V) under composition
    float P = cL, V = v;
#pragma unroll
    for (int d = 1; d < 64; d <<= 1) {
        float Pp = __shfl_up(P, d);
        float Vp = __shfl_up(V, d);
        if (lane >= d) { V = fmaf(P, Vp, V); P *= Pp; }
    }

    // ---- cross-wave exchange (32 B LDS, single barrier)
    if (lane == 63) { wP[wave] = P; wV[wave] = V; }
    __syncthreads();
    float prefV = 0.0f;
#pragma unroll
    for (int k = 0; k < NW - 1; ++k) {
        if (k < wave) prefV = fmaf(wP[k], prefV, wV[k]);
    }

    // exclusive prefix: true state entering my segment
    float Pex = __shfl_up(P, 1);
    float Vex = __shfl_up(V, 1);
    if (lane == 0) { Pex = 1.0f; Vex = 0.0f; }
    const float s = fmaf(Pex, prefV, Vex);

    // ---- linear fixup: z[j] = z_local[j] + s * c^(j+1)
    float m = s;
#pragma unroll
    for (int j = 0; j < LSEG; ++j) {
        m *= c;
        u[j] += m;
    }

    // ---- store: per-float4 guard (t0 and segs both multiples of 4)
    if (interior) {
#pragma unroll
        for (int i = 0; i < LSEG / 4; ++i) {
            int p = segs + 4 * i;
            if (p >= t0) {
                *(float4*)(out + p) = make_float4(u[4*i+0], u[4*i+1],
                                                  u[4*i+2], u[4*i+3]);
            }
        }
    } else {
#pragma unroll
        for (int j = 0; j < LSEG; ++j) {
            int p = segs + j;
            if (p >= t0 && p < T) out[p] = u[j];
        }
    }
}

extern "C" void kernel_launch(void* const* d_in, const int* in_sizes, int n_in,
                              void* d_out, int out_size, void* d_ws, size_t ws_size,
                              hipStream_t stream) {
    const float* x       = (const float*)d_in[0];
    const float* w_alpha = (const float*)d_in[1];
    float*       out     = (float*)d_out;
    const int T = in_sizes[0];

    const int nblocks = (T + NB - 1) / NB;   // 1024 for T=4194304
    diffema_kernel<<<nblocks, BLOCK, 0, stream>>>(x, w_alpha, out, T);
}